// Round 17
// baseline (264.875 us; speedup 1.0000x reference)
//
#include <hip/hip_runtime.h>
#include <hip/hip_bf16.h>
#include <stdint.h>

typedef __bf16 bf16x8 __attribute__((ext_vector_type(8)));
typedef float f32x4 __attribute__((ext_vector_type(4)));
typedef unsigned short us4v __attribute__((ext_vector_type(4)));
typedef unsigned short us8v __attribute__((ext_vector_type(8)));
typedef unsigned int u32x4 __attribute__((ext_vector_type(4)));

#define B_   2
#define T_   2048
#define C_   1024
#define NH_  16
#define HD_  64

__device__ __forceinline__ unsigned short f2bf(float f) {
  unsigned int u = __builtin_bit_cast(unsigned int, f);
  u += 0x7fffu + ((u >> 16) & 1u);           // RNE
  return (unsigned short)(u >> 16);
}
__device__ __forceinline__ float bf2f(unsigned short u) {
  unsigned int x = ((unsigned int)u) << 16;
  return __builtin_bit_cast(float, x);
}

__device__ __forceinline__ void gload16(const void* g, void* l) {
  __builtin_amdgcn_global_load_lds(
      (const __attribute__((address_space(1))) unsigned int*)g,
      (__attribute__((address_space(3))) unsigned int*)l, 16, 0, 0);
}

__device__ __forceinline__ f32x4 mfma16(bf16x8 a, bf16x8 b, f32x4 c) {
  return __builtin_amdgcn_mfma_f32_16x16x32_bf16(a, b, c, 0, 0, 0);
}

__device__ __forceinline__ void keep(bf16x8 v) {
  u32x4 k = __builtin_bit_cast(u32x4, v);
  asm volatile("" :: "v"(k));
}

// ---------------- fused prep: cast_x + both weight transposes, ONE dispatch ----------------
__global__ __launch_bounds__(256) void prep_kernel(const float* __restrict__ x,
                                                   unsigned short* __restrict__ xb,
                                                   const float* __restrict__ w_qkv,
                                                   unsigned short* __restrict__ wqkvT,
                                                   const float* __restrict__ w_proj,
                                                   unsigned short* __restrict__ wprojT) {
  __shared__ float tile[32][33];
  const int b = blockIdx.x, t = threadIdx.x;
  if (b < 4096) {
    int i = b * 256 + t;
    float4 f = ((const float4*)x)[i];
    us4v o; o[0] = f2bf(f.x); o[1] = f2bf(f.y); o[2] = f2bf(f.z); o[3] = f2bf(f.w);
    ((us4v*)xb)[i] = o;
    return;
  }
  const float* w; unsigned short* wT; int N, tb;
  if (b < 7168) { tb = b - 4096; w = w_qkv;  wT = wqkvT;  N = 3 * C_; }
  else          { tb = b - 7168; w = w_proj; wT = wprojT; N = C_; }
  const int nx = N / 32;
  const int n0 = (tb % nx) * 32, k0 = (tb / nx) * 32;
  const int tx = t & 31, ty = t >> 5;   // 32 x 8
  #pragma unroll
  for (int i = 0; i < 4; ++i)
    tile[ty + 8*i][tx] = w[(size_t)(k0 + ty + 8*i) * N + n0 + tx];
  __syncthreads();
  #pragma unroll
  for (int i = 0; i < 4; ++i)
    wT[(size_t)(n0 + ty + 8*i) * C_ + k0 + tx] = f2bf(tile[tx][ty + 8*i]);
}

// ---------------- GEMM core (verified round 0 — structural ceiling ~870 TF) ----------------
__device__ __forceinline__ void gemm_core(const unsigned short* __restrict__ A,
                                          const unsigned short* __restrict__ Bt,
                                          int K, int m0, int n0,
                                          unsigned short* lA, unsigned short* lB,
                                          f32x4 acc[4][4]) {
  const int t = threadIdx.x;
  const int lane = t & 63, w = t >> 6;
  const int wm = w >> 1, wn = w & 1;
  const int g = lane >> 4, r16 = lane & 15;
  #pragma unroll
  for (int i = 0; i < 4; ++i)
    #pragma unroll
    for (int j = 0; j < 4; ++j) acc[i][j] = (f32x4){0.f, 0.f, 0.f, 0.f};

  for (int k0 = 0; k0 < K; k0 += 64) {
    #pragma unroll
    for (int i = 0; i < 4; ++i) {
      int slot = i * 256 + t;
      int r = slot >> 3, p = slot & 7;
      int q = p ^ (r & 7);
      gload16(A  + (size_t)(m0 + r) * K + k0 + q * 8, lA + slot * 8);
      gload16(Bt + (size_t)(n0 + r) * K + k0 + q * 8, lB + slot * 8);
    }
    asm volatile("s_waitcnt vmcnt(0)" ::: "memory");
    __syncthreads();

    bf16x8 af[4][2], bfr[4][2];
    #pragma unroll
    for (int mi = 0; mi < 4; ++mi)
      #pragma unroll
      for (int kk = 0; kk < 2; ++kk) {
        int r = wm * 64 + mi * 16 + r16;
        int ps = (kk * 4 + g) ^ (r & 7);
        af[mi][kk] = *(const bf16x8*)(lA + r * 64 + ps * 8);
      }
    #pragma unroll
    for (int ni = 0; ni < 4; ++ni)
      #pragma unroll
      for (int kk = 0; kk < 2; ++kk) {
        int r = wn * 64 + ni * 16 + r16;
        int ps = (kk * 4 + g) ^ (r & 7);
        bfr[ni][kk] = *(const bf16x8*)(lB + r * 64 + ps * 8);
      }
    #pragma unroll
    for (int mi = 0; mi < 4; ++mi)
      #pragma unroll
      for (int ni = 0; ni < 4; ++ni)
        #pragma unroll
        for (int kk = 0; kk < 2; ++kk)
          acc[mi][ni] = mfma16(af[mi][kk], bfr[ni][kk], acc[mi][ni]);
    __syncthreads();
  }
}

// XCD-aware bijective swizzle of the linear workgroup id (nwg % 8 == 0)
__device__ __forceinline__ int xcd_swz(int flat, int nwg) {
  int cpx = nwg >> 3;
  return (flat & 7) * cpx + (flat >> 3);
}

__global__ __launch_bounds__(256) void gemm_qkv_kernel(const unsigned short* __restrict__ xb,
                                                       const unsigned short* __restrict__ wT,
                                                       unsigned short* __restrict__ qb,
                                                       unsigned short* __restrict__ kb,
                                                       unsigned short* __restrict__ vb) {
  __shared__ unsigned short lA[128 * 64];
  __shared__ unsigned short lB[128 * 64];
  f32x4 acc[4][4];
  const int nbx = 3 * C_ / 128;
  int flat = xcd_swz(blockIdx.y * nbx + blockIdx.x, nbx * ((B_ * T_) / 128));
  const int m0 = (flat / nbx) * 128, n0 = (flat % nbx) * 128;
  gemm_core(xb, wT, C_, m0, n0, lA, lB, acc);
  const int t = threadIdx.x, lane = t & 63, w = t >> 6;
  const int wm = w >> 1, wn = w & 1, g = lane >> 4, r16 = lane & 15;
  #pragma unroll
  for (int mi = 0; mi < 4; ++mi)
    #pragma unroll
    for (int ni = 0; ni < 4; ++ni)
      #pragma unroll
      for (int j = 0; j < 4; ++j) {
        int gm = m0 + wm * 64 + mi * 16 + g * 4 + j;
        int gn = n0 + wn * 64 + ni * 16 + r16;
        int b = gm >> 11, tt = gm & 2047;
        int s = gn >> 10, rem = gn & 1023;
        int h = rem >> 6, d = rem & 63;
        unsigned short val = f2bf(acc[mi][ni][j]);
        size_t idx = ((size_t)(b * NH_ + h) * T_ + tt) * HD_ + d;
        if (s == 0)      qb[idx] = val;
        else if (s == 1) kb[idx] = val;
        else             vb[idx] = val;
      }
}

__global__ __launch_bounds__(256) void gemm_proj_kernel(const unsigned short* __restrict__ ab,
                                                        const unsigned short* __restrict__ wT,
                                                        float* __restrict__ out) {
  __shared__ unsigned short lA[128 * 64];
  __shared__ unsigned short lB[128 * 64];
  f32x4 acc[4][4];
  const int nbx = C_ / 128;
  int flat = xcd_swz(blockIdx.y * nbx + blockIdx.x, nbx * ((B_ * T_) / 128));
  const int m0 = (flat / nbx) * 128, n0 = (flat % nbx) * 128;
  gemm_core(ab, wT, C_, m0, n0, lA, lB, acc);
  const int t = threadIdx.x, lane = t & 63, w = t >> 6;
  const int wm = w >> 1, wn = w & 1, g = lane >> 4, r16 = lane & 15;
  #pragma unroll
  for (int mi = 0; mi < 4; ++mi)
    #pragma unroll
    for (int ni = 0; ni < 4; ++ni)
      #pragma unroll
      for (int j = 0; j < 4; ++j) {
        int gm = m0 + wm * 64 + mi * 16 + g * 4 + j;
        int gn = n0 + wn * 64 + ni * 16 + r16;
        out[(size_t)gm * C_ + gn] = acc[mi][ni][j];
      }
}

// ---------------- Flash attention v13 (templated for phase ablation) ----------------
// V=0 full (real output). Ablations (scratch output, timing only):
// V=1 NOSM (skip softmax; pack P from raw S), V=2 NOPV (skip PV MFMAs,
// keepalive pf+vf), V=4 NOQK (skip QK MFMAs, keepalive qf+kf).
template<int V>
__global__ __launch_bounds__(256, 4) void attn_tmpl(const unsigned short* __restrict__ qb,
                                                    const unsigned short* __restrict__ kb,
                                                    const unsigned short* __restrict__ vb,
                                                    unsigned short* __restrict__ ao,
                                                    unsigned short* __restrict__ partB,
                                                    float* __restrict__ mlbuf) {
  __shared__ unsigned short LDS[20480];
  const int L = blockIdx.x;
  const int inner = L >> 3;
  const int bh = (L & 7) * 4 + (inner / 48);
  const int bx = inner % 48;
  int tile, kvLo, kvHi, mode;
  if (bx < 16)      { tile = 16 + bx; kvLo = 0;  kvHi = 16;       mode = 1; }
  else if (bx < 32) { tile = 47 - bx; kvLo = 16; kvHi = tile + 1; mode = 2; }
  else              { tile = 47 - bx; kvLo = 0;  kvHi = tile + 1; mode = 0; }
  const int qt0 = tile * 64;
  const int len = kvHi - kvLo;
  const int t = threadIdx.x, lane = t & 63, w4 = t >> 6;
  const int g = lane >> 4, r16 = lane & 15;

  const unsigned short* Q  = qb + (size_t)bh * (T_ * HD_);
  const unsigned short* Kp = kb + (size_t)bh * (T_ * HD_);
  const unsigned short* Vp = vb + (size_t)bh * (T_ * HD_);

  bf16x8 qf[2];
  {
    int qrow = qt0 + w4 * 16 + r16;
    #pragma unroll
    for (int kk = 0; kk < 2; ++kk) {
      us8v raw = *(const us8v*)(Q + (size_t)qrow * HD_ + kk * 32 + g * 8);
      bf16x8 qv;
      #pragma unroll
      for (int j = 0; j < 8; ++j) qv[j] = (__bf16)(bf2f(raw[j]) * 0.125f);
      qf[kk] = qv;
    }
  }

  f32x4 o[4];
  #pragma unroll
  for (int c = 0; c < 4; ++c) o[c] = (f32x4){0.f, 0.f, 0.f, 0.f};
  float mrun = -__builtin_inff(), lrun = 0.f;

  const int kr0 = t >> 3,         kp0 = (t & 7) ^ (kr0 & 7);
  const int kr1 = (t + 256) >> 3, kp1 = (t & 7) ^ (kr1 & 7);
  const int colp = (lane & 32) | ((lane & 12) << 1) | ((lane >> 2) & 4) | (lane & 3);
  const int cslot = colp >> 3, cwithin = colp & 7;

  gload16(Kp + (size_t)(kvLo * 64 + kr0) * HD_ + kp0 * 8, LDS + t * 8);
  gload16(Kp + (size_t)(kvLo * 64 + kr1) * HD_ + kp1 * 8, LDS + (t + 256) * 8);
  us8v nvA0 = *(const us8v*)(Vp + (size_t)(kvLo * 64 + lane) * HD_ + w4 * 16);
  us8v nvA1 = *(const us8v*)(Vp + (size_t)(kvLo * 64 + lane) * HD_ + w4 * 16 + 8);
  us8v nvB0, nvB1;
  if (len > 1) {
    const int k1 = (kvLo + 1) * 64;
    gload16(Kp + (size_t)(k1 + kr0) * HD_ + kp0 * 8, LDS + 4096 + t * 8);
    gload16(Kp + (size_t)(k1 + kr1) * HD_ + kp1 * 8, LDS + 4096 + (t + 256) * 8);
    nvB0 = *(const us8v*)(Vp + (size_t)(k1 + lane) * HD_ + w4 * 16);
    nvB1 = *(const us8v*)(Vp + (size_t)(k1 + lane) * HD_ + w4 * 16 + 8);
  }

  for (int ii = 0; ii < len; ++ii) {
    const int it = kvLo + ii;
    const unsigned short* Kl = LDS + (ii % 3) * 4096;
    unsigned short* Vt = LDS + 12288 + (ii & 1) * 4096;

    if (ii + 1 < len) { asm volatile("s_waitcnt vmcnt(4)" ::: "memory"); }
    else              { asm volatile("s_waitcnt vmcnt(0)" ::: "memory"); }
    {
      us8v v0, v1;
      if (ii & 1) { v0 = nvB0; v1 = nvB1; } else { v0 = nvA0; v1 = nvA1; }
      #pragma unroll
      for (int u = 0; u < 8; ++u) {
        int d = w4 * 16 + u;
        Vt[d * 64 + ((cslot ^ u) << 3) + cwithin] = v0[u];
      }
      #pragma unroll
      for (int u = 0; u < 8; ++u) {
        int d = w4 * 16 + 8 + u;
        Vt[d * 64 + ((cslot ^ u) << 3) + cwithin] = v1[u];
      }
    }
    __syncthreads();

    if (ii + 2 < len) {
      const int kn = (it + 2) * 64;
      unsigned short* Kn = LDS + ((ii + 2) % 3) * 4096;
      gload16(Kp + (size_t)(kn + kr0) * HD_ + kp0 * 8, Kn + t * 8);
      gload16(Kp + (size_t)(kn + kr1) * HD_ + kp1 * 8, Kn + (t + 256) * 8);
      if (ii & 1) {
        nvB0 = *(const us8v*)(Vp + (size_t)(kn + lane) * HD_ + w4 * 16);
        nvB1 = *(const us8v*)(Vp + (size_t)(kn + lane) * HD_ + w4 * 16 + 8);
      } else {
        nvA0 = *(const us8v*)(Vp + (size_t)(kn + lane) * HD_ + w4 * 16);
        nvA1 = *(const us8v*)(Vp + (size_t)(kn + lane) * HD_ + w4 * 16 + 8);
      }
    }

    {
      f32x4 s4t[4];
      #pragma unroll
      for (int c = 0; c < 4; ++c) s4t[c] = (f32x4){0.f, 0.f, 0.f, 0.f};
      if constexpr (V != 4) {
        __builtin_amdgcn_s_setprio(1);
        #pragma unroll
        for (int c = 0; c < 4; ++c)
          #pragma unroll
          for (int kk = 0; kk < 2; ++kk) {
            int r = c * 16 + r16;
            int ps = (kk * 4 + g) ^ (r & 7);
            bf16x8 kf = *(const bf16x8*)(Kl + r * 64 + ps * 8);
            s4t[c] = mfma16(kf, qf[kk], s4t[c]);
          }
        __builtin_amdgcn_s_setprio(0);
      } else {
        // NOQK: keep kf reads + qf alive; cheap s4t init
        keep(qf[0]); keep(qf[1]);
        #pragma unroll
        for (int c = 0; c < 4; ++c)
          #pragma unroll
          for (int kk = 0; kk < 2; ++kk) {
            int r = c * 16 + r16;
            int ps = (kk * 4 + g) ^ (r & 7);
            bf16x8 kf = *(const bf16x8*)(Kl + r * 64 + ps * 8);
            keep(kf);
          }
        #pragma unroll
        for (int c = 0; c < 4; ++c) s4t[c] = (f32x4){0.1f, 0.2f, 0.3f, (float)c};
      }
      if (it == tile) {
        int qloc = w4 * 16 + r16;
        #pragma unroll
        for (int c = 0; c < 4; ++c)
          #pragma unroll
          for (int j = 0; j < 4; ++j)
            if (c * 16 + g * 4 + j > qloc) s4t[c][j] = -1e30f;
      }
      if constexpr (V != 1) {
        float t0 = fmaxf(fmaxf(s4t[0][0], s4t[0][1]), s4t[0][2]);
        float t1 = fmaxf(fmaxf(s4t[0][3], s4t[1][0]), s4t[1][1]);
        float t2 = fmaxf(fmaxf(s4t[1][2], s4t[1][3]), s4t[2][0]);
        float t3 = fmaxf(fmaxf(s4t[2][1], s4t[2][2]), s4t[2][3]);
        float t4 = fmaxf(fmaxf(s4t[3][0], s4t[3][1]), s4t[3][2]);
        float mx = fmaxf(fmaxf(fmaxf(t0, t1), fmaxf(t2, t3)),
                         fmaxf(t4, s4t[3][3]));
        mx = fmaxf(mx, __shfl_xor(mx, 16));
        mx = fmaxf(mx, __shfl_xor(mx, 32));
        if (!__all(mx - mrun <= 8.0f)) {
          float mn = fmaxf(mrun, mx);
          float alpha = __expf(mrun - mn);
          mrun = mn;
          lrun *= alpha;
          #pragma unroll
          for (int c = 0; c < 4; ++c)
            #pragma unroll
            for (int j = 0; j < 4; ++j) o[c][j] *= alpha;
        }
        float ps4[4];
        #pragma unroll
        for (int c = 0; c < 4; ++c) {
          #pragma unroll
          for (int j = 0; j < 4; ++j) s4t[c][j] = __expf(s4t[c][j] - mrun);
          ps4[c] = (s4t[c][0] + s4t[c][1]) + (s4t[c][2] + s4t[c][3]);
        }
        float rs = (ps4[0] + ps4[1]) + (ps4[2] + ps4[3]);
        rs += __shfl_xor(rs, 16);
        rs += __shfl_xor(rs, 32);
        lrun += rs;
      }

      bf16x8 pf[2];
      #pragma unroll
      for (int kk = 0; kk < 2; ++kk) {
        bf16x8 p;
        #pragma unroll
        for (int j = 0; j < 4; ++j) {
          p[j]     = (__bf16)s4t[2 * kk][j];
          p[4 + j] = (__bf16)s4t[2 * kk + 1][j];
        }
        pf[kk] = p;
      }
      if constexpr (V != 2) {
        __builtin_amdgcn_s_setprio(1);
        #pragma unroll
        for (int c = 0; c < 4; ++c) {
          int rv = c * 16 + r16;
          #pragma unroll
          for (int kk = 0; kk < 2; ++kk) {
            int slot = (4 * kk + g) ^ (r16 & 7);
            bf16x8 vf = *(const bf16x8*)(Vt + rv * 64 + slot * 8);
            o[c] = mfma16(vf, pf[kk], o[c]);
          }
        }
        __builtin_amdgcn_s_setprio(0);
      } else {
        // NOPV: keep pf + vf reads alive
        keep(pf[0]); keep(pf[1]);
        #pragma unroll
        for (int c = 0; c < 4; ++c) {
          int rv = c * 16 + r16;
          #pragma unroll
          for (int kk = 0; kk < 2; ++kk) {
            int slot = (4 * kk + g) ^ (r16 & 7);
            bf16x8 vf = *(const bf16x8*)(Vt + rv * 64 + slot * 8);
            keep(vf);
          }
        }
      }
    }
  }

  if (mode && g == 0) {
    int prow = (bh * 16 + (tile - 16)) * 64 + w4 * 16 + r16;
    float* mlp = mlbuf + (size_t)prow * 4;
    if (mode == 1) { mlp[0] = mrun; mlp[1] = lrun; }
    else           { mlp[2] = mrun; mlp[3] = lrun; }
  }

  unsigned short* ep = LDS + (len % 3) * 4096 + w4 * 1024;
  float inv = 1.f / lrun;
  #pragma unroll
  for (int c = 0; c < 4; ++c) {
    us4v pk;
    #pragma unroll
    for (int j = 0; j < 4; ++j) pk[j] = f2bf(o[c][j] * inv);
    int slot = (4 * c + g) ^ r16;
    *(us4v*)(ep + r16 * 64 + slot * 4) = pk;
  }
  asm volatile("s_waitcnt lgkmcnt(0)" ::: "memory");
  __builtin_amdgcn_sched_barrier(0);
  {
    int q = lane >> 2, seg = lane & 3;
    us4v a0 = *(const us4v*)(ep + q * 64 + (((seg * 4 + 0) ^ q) & 15) * 4);
    us4v a1 = *(const us4v*)(ep + q * 64 + (((seg * 4 + 1) ^ q) & 15) * 4);
    us4v a2 = *(const us4v*)(ep + q * 64 + (((seg * 4 + 2) ^ q) & 15) * 4);
    us4v a3 = *(const us4v*)(ep + q * 64 + (((seg * 4 + 3) ^ q) & 15) * 4);
    us8v o0 = {a0[0],a0[1],a0[2],a0[3],a1[0],a1[1],a1[2],a1[3]};
    us8v o1 = {a2[0],a2[1],a2[2],a2[3],a3[0],a3[1],a3[2],a3[3]};
    if (mode != 2) {
      size_t rowg = (size_t)(bh >> 4) * T_ + qt0 + w4 * 16 + q;
      int colg = (bh & 15) * 64 + seg * 16;
      *(us8v*)(ao + rowg * C_ + colg)     = o0;
      *(us8v*)(ao + rowg * C_ + colg + 8) = o1;
    } else {
      size_t prow = (size_t)(bh * 16 + (tile - 16)) * 64 + w4 * 16 + q;
      *(us8v*)(partB + prow * 64 + seg * 16)     = o0;
      *(us8v*)(partB + prow * 64 + seg * 16 + 8) = o1;
    }
  }
}

// ---------------- merge kernel ----------------
__global__ __launch_bounds__(256) void attn_merge_kernel(unsigned short* __restrict__ ao,
                                                         const unsigned short* __restrict__ partB,
                                                         const float* __restrict__ mlbuf) {
  const int blk = blockIdx.x;
  const int bh = blk >> 4, ti = blk & 15;
  const int t = threadIdx.x;
  const int row = t >> 2, seg = t & 3;
  const size_t prow = (size_t)(bh * 16 + ti) * 64 + row;
  const float* mlp = mlbuf + prow * 4;
  float mA = mlp[0], lA = mlp[1], mB = mlp[2], lB = mlp[3];
  float m = fmaxf(mA, mB);
  float wA = lA * __expf(mA - m), wB = lB * __expf(mB - m);
  float rinv = 1.f / (wA + wB);
  wA *= rinv; wB *= rinv;
  size_t rowg = (size_t)(bh >> 4) * T_ + (16 + ti) * 64 + row;
  unsigned short* aop = ao + rowg * C_ + (bh & 15) * 64 + seg * 16;
  const unsigned short* obp = partB + prow * 64 + seg * 16;
  us8v oa0 = *(const us8v*)(aop);
  us8v oa1 = *(const us8v*)(aop + 8);
  us8v ob0 = *(const us8v*)(obp);
  us8v ob1 = *(const us8v*)(obp + 8);
  us8v r0, r1;
  #pragma unroll
  for (int j = 0; j < 8; ++j) {
    r0[j] = f2bf(bf2f(oa0[j]) * wA + bf2f(ob0[j]) * wB);
    r1[j] = f2bf(bf2f(oa1[j]) * wA + bf2f(ob1[j]) * wB);
  }
  *(us8v*)(aop)     = r0;
  *(us8v*)(aop + 8) = r1;
}

// ---------------- launch ----------------
extern "C" void kernel_launch(void* const* d_in, const int* in_sizes, int n_in,
                              void* d_out, int out_size, void* d_ws, size_t ws_size,
                              hipStream_t stream) {
  const float* x      = (const float*)d_in[0];
  const float* w_qkv  = (const float*)d_in[1];
  const float* w_proj = (const float*)d_in[2];
  float* out = (float*)d_out;
  char* ws = (char*)d_ws;

  unsigned short* xb     = (unsigned short*)(ws);              // 8 MB (reused as ao)
  unsigned short* wqkvT  = (unsigned short*)(ws + 8388608);    // 6 MB (reused: partB+ml)
  unsigned short* wprojT = (unsigned short*)(ws + 14680064);   // 2 MB
  unsigned short* qb     = (unsigned short*)(ws + 16777216);   // 8 MB
  unsigned short* kb     = (unsigned short*)(ws + 25165824);   // 8 MB
  unsigned short* vb     = (unsigned short*)(ws + 33554432);   // 8 MB
  unsigned short* ao     = xb;
  unsigned short* partB  = wqkvT;                              // 4 MB
  float*          mlbuf  = (float*)(ws + 8388608 + 4194304);   // 512 KB
  // ablation scratch: d_out region (overwritten by gemm_proj afterwards)
  unsigned short* aoScr  = (unsigned short*)d_out;             // needs 8 MB of 16.8 MB

  prep_kernel<<<8192, 256, 0, stream>>>(x, xb, w_qkv, wqkvT, w_proj, wprojT);
  gemm_qkv_kernel<<<dim3(3 * C_ / 128, (B_ * T_) / 128), 256, 0, stream>>>(
      xb, wqkvT, qb, kb, vb);
  attn_tmpl<0><<<dim3(1536), 256, 0, stream>>>(qb, kb, vb, ao, partB, mlbuf);
  attn_merge_kernel<<<512, 256, 0, stream>>>(ao, partB, mlbuf);
  // ---- phase-ablation probes (outputs dead; timing read from rocprof) ----
  attn_tmpl<1><<<dim3(1536), 256, 0, stream>>>(qb, kb, vb, aoScr, partB, mlbuf);
  attn_tmpl<2><<<dim3(1536), 256, 0, stream>>>(qb, kb, vb, aoScr, partB, mlbuf);
  attn_tmpl<4><<<dim3(1536), 256, 0, stream>>>(qb, kb, vb, aoScr, partB, mlbuf);
  gemm_proj_kernel<<<dim3(C_ / 128, (B_ * T_) / 128), 256, 0, stream>>>(
      ao, wprojT, out);
}

// Round 18
// 137.290 us; speedup vs baseline: 1.9293x; 1.9293x over previous
//
#include <hip/hip_runtime.h>
#include <hip/hip_bf16.h>
#include <stdint.h>

typedef __bf16 bf16x8 __attribute__((ext_vector_type(8)));
typedef float f32x4 __attribute__((ext_vector_type(4)));
typedef unsigned short us4v __attribute__((ext_vector_type(4)));
typedef unsigned short us8v __attribute__((ext_vector_type(8)));

#define B_   2
#define T_   2048
#define C_   1024
#define NH_  16
#define HD_  64

__device__ __forceinline__ unsigned short f2bf(float f) {
  unsigned int u = __builtin_bit_cast(unsigned int, f);
  u += 0x7fffu + ((u >> 16) & 1u);           // RNE
  return (unsigned short)(u >> 16);
}
__device__ __forceinline__ float bf2f(unsigned short u) {
  unsigned int x = ((unsigned int)u) << 16;
  return __builtin_bit_cast(float, x);
}

__device__ __forceinline__ void gload16(const void* g, void* l) {
  __builtin_amdgcn_global_load_lds(
      (const __attribute__((address_space(1))) unsigned int*)g,
      (__attribute__((address_space(3))) unsigned int*)l, 16, 0, 0);
}

__device__ __forceinline__ f32x4 mfma16(bf16x8 a, bf16x8 b, f32x4 c) {
  return __builtin_amdgcn_mfma_f32_16x16x32_bf16(a, b, c, 0, 0, 0);
}

// ---------------- fused prep: cast_x + both weight transposes, ONE dispatch ----------------
__global__ __launch_bounds__(256) void prep_kernel(const float* __restrict__ x,
                                                   unsigned short* __restrict__ xb,
                                                   const float* __restrict__ w_qkv,
                                                   unsigned short* __restrict__ wqkvT,
                                                   const float* __restrict__ w_proj,
                                                   unsigned short* __restrict__ wprojT) {
  __shared__ float tile[32][33];
  const int b = blockIdx.x, t = threadIdx.x;
  if (b < 4096) {
    int i = b * 256 + t;
    float4 f = ((const float4*)x)[i];
    us4v o; o[0] = f2bf(f.x); o[1] = f2bf(f.y); o[2] = f2bf(f.z); o[3] = f2bf(f.w);
    ((us4v*)xb)[i] = o;
    return;
  }
  const float* w; unsigned short* wT; int N, tb;
  if (b < 7168) { tb = b - 4096; w = w_qkv;  wT = wqkvT;  N = 3 * C_; }
  else          { tb = b - 7168; w = w_proj; wT = wprojT; N = C_; }
  const int nx = N / 32;
  const int n0 = (tb % nx) * 32, k0 = (tb / nx) * 32;
  const int tx = t & 31, ty = t >> 5;   // 32 x 8
  #pragma unroll
  for (int i = 0; i < 4; ++i)
    tile[ty + 8*i][tx] = w[(size_t)(k0 + ty + 8*i) * N + n0 + tx];
  __syncthreads();
  #pragma unroll
  for (int i = 0; i < 4; ++i)
    wT[(size_t)(n0 + ty + 8*i) * C_ + k0 + tx] = f2bf(tile[tx][ty + 8*i]);
}

// ---------------- GEMM core (verified round 0 — structural ceiling ~870 TF) ----------------
__device__ __forceinline__ void gemm_core(const unsigned short* __restrict__ A,
                                          const unsigned short* __restrict__ Bt,
                                          int K, int m0, int n0,
                                          unsigned short* lA, unsigned short* lB,
                                          f32x4 acc[4][4]) {
  const int t = threadIdx.x;
  const int lane = t & 63, w = t >> 6;
  const int wm = w >> 1, wn = w & 1;
  const int g = lane >> 4, r16 = lane & 15;
  #pragma unroll
  for (int i = 0; i < 4; ++i)
    #pragma unroll
    for (int j = 0; j < 4; ++j) acc[i][j] = (f32x4){0.f, 0.f, 0.f, 0.f};

  for (int k0 = 0; k0 < K; k0 += 64) {
    #pragma unroll
    for (int i = 0; i < 4; ++i) {
      int slot = i * 256 + t;
      int r = slot >> 3, p = slot & 7;
      int q = p ^ (r & 7);
      gload16(A  + (size_t)(m0 + r) * K + k0 + q * 8, lA + slot * 8);
      gload16(Bt + (size_t)(n0 + r) * K + k0 + q * 8, lB + slot * 8);
    }
    asm volatile("s_waitcnt vmcnt(0)" ::: "memory");
    __syncthreads();

    bf16x8 af[4][2], bfr[4][2];
    #pragma unroll
    for (int mi = 0; mi < 4; ++mi)
      #pragma unroll
      for (int kk = 0; kk < 2; ++kk) {
        int r = wm * 64 + mi * 16 + r16;
        int ps = (kk * 4 + g) ^ (r & 7);
        af[mi][kk] = *(const bf16x8*)(lA + r * 64 + ps * 8);
      }
    #pragma unroll
    for (int ni = 0; ni < 4; ++ni)
      #pragma unroll
      for (int kk = 0; kk < 2; ++kk) {
        int r = wn * 64 + ni * 16 + r16;
        int ps = (kk * 4 + g) ^ (r & 7);
        bfr[ni][kk] = *(const bf16x8*)(lB + r * 64 + ps * 8);
      }
    #pragma unroll
    for (int mi = 0; mi < 4; ++mi)
      #pragma unroll
      for (int ni = 0; ni < 4; ++ni)
        #pragma unroll
        for (int kk = 0; kk < 2; ++kk)
          acc[mi][ni] = mfma16(af[mi][kk], bfr[ni][kk], acc[mi][ni]);
    __syncthreads();
  }
}

// XCD-aware bijective swizzle of the linear workgroup id (nwg % 8 == 0)
__device__ __forceinline__ int xcd_swz(int flat, int nwg) {
  int cpx = nwg >> 3;
  return (flat & 7) * cpx + (flat >> 3);
}

__global__ __launch_bounds__(256) void gemm_qkv_kernel(const unsigned short* __restrict__ xb,
                                                       const unsigned short* __restrict__ wT,
                                                       unsigned short* __restrict__ qb,
                                                       unsigned short* __restrict__ kb,
                                                       unsigned short* __restrict__ vb) {
  __shared__ unsigned short lA[128 * 64];
  __shared__ unsigned short lB[128 * 64];
  f32x4 acc[4][4];
  const int nbx = 3 * C_ / 128;
  int flat = xcd_swz(blockIdx.y * nbx + blockIdx.x, nbx * ((B_ * T_) / 128));
  const int m0 = (flat / nbx) * 128, n0 = (flat % nbx) * 128;
  gemm_core(xb, wT, C_, m0, n0, lA, lB, acc);
  const int t = threadIdx.x, lane = t & 63, w = t >> 6;
  const int wm = w >> 1, wn = w & 1, g = lane >> 4, r16 = lane & 15;
  #pragma unroll
  for (int mi = 0; mi < 4; ++mi)
    #pragma unroll
    for (int ni = 0; ni < 4; ++ni)
      #pragma unroll
      for (int j = 0; j < 4; ++j) {
        int gm = m0 + wm * 64 + mi * 16 + g * 4 + j;
        int gn = n0 + wn * 64 + ni * 16 + r16;
        int b = gm >> 11, tt = gm & 2047;
        int s = gn >> 10, rem = gn & 1023;
        int h = rem >> 6, d = rem & 63;
        unsigned short val = f2bf(acc[mi][ni][j]);
        size_t idx = ((size_t)(b * NH_ + h) * T_ + tt) * HD_ + d;
        if (s == 0)      qb[idx] = val;
        else if (s == 1) kb[idx] = val;
        else             vb[idx] = val;
      }
}

__global__ __launch_bounds__(256) void gemm_proj_kernel(const unsigned short* __restrict__ ab,
                                                        const unsigned short* __restrict__ wT,
                                                        float* __restrict__ out) {
  __shared__ unsigned short lA[128 * 64];
  __shared__ unsigned short lB[128 * 64];
  f32x4 acc[4][4];
  const int nbx = C_ / 128;
  int flat = xcd_swz(blockIdx.y * nbx + blockIdx.x, nbx * ((B_ * T_) / 128));
  const int m0 = (flat / nbx) * 128, n0 = (flat % nbx) * 128;
  gemm_core(ab, wT, C_, m0, n0, lA, lB, acc);
  const int t = threadIdx.x, lane = t & 63, w = t >> 6;
  const int wm = w >> 1, wn = w & 1, g = lane >> 4, r16 = lane & 15;
  #pragma unroll
  for (int mi = 0; mi < 4; ++mi)
    #pragma unroll
    for (int ni = 0; ni < 4; ++ni)
      #pragma unroll
      for (int j = 0; j < 4; ++j) {
        int gm = m0 + wm * 64 + mi * 16 + g * 4 + j;
        int gn = n0 + wn * 64 + ni * 16 + r16;
        out[(size_t)gm * C_ + gn] = acc[mi][ni][j];
      }
}

// ---------------- Flash attention v14: kv-split + 32 q-rows/wave ----------------
// Ablation-proven LDS-throughput-bound => halve LDS reads per unit work.
// Block = one 64-row tile x kv-window, 2 waves x 32 rows, 128 threads.
// Each kf/vf b128 read feeds TWO MFMAs (v7-verified datapath on the
// v13-verified kv-split scaffolding). LDS 40 KB: K0/K1/K2 + V0/V1 as before.
__global__ __launch_bounds__(128, 2) void attn_kernel(const unsigned short* __restrict__ qb,
                                                      const unsigned short* __restrict__ kb,
                                                      const unsigned short* __restrict__ vb,
                                                      unsigned short* __restrict__ ao,
                                                      unsigned short* __restrict__ partB,
                                                      float* __restrict__ mlbuf) {
  __shared__ unsigned short LDS[20480];
  const int L = blockIdx.x;
  const int inner = L >> 3;
  const int bh = (L & 7) * 4 + (inner / 48);
  const int bx = inner % 48;
  int tile, kvLo, kvHi, mode;   // mode: 0=full, 1=halfA, 2=halfB
  if (bx < 16)      { tile = 16 + bx; kvLo = 0;  kvHi = 16;       mode = 1; }
  else if (bx < 32) { tile = 47 - bx; kvLo = 16; kvHi = tile + 1; mode = 2; }
  else              { tile = 47 - bx; kvLo = 0;  kvHi = tile + 1; mode = 0; }
  const int qt0 = tile * 64;
  const int len = kvHi - kvLo;
  const int t = threadIdx.x, lane = t & 63, w2 = t >> 6;   // w2 in {0,1}
  const int g = lane >> 4, r16 = lane & 15;

  const unsigned short* Q  = qb + (size_t)bh * (T_ * HD_);
  const unsigned short* Kp = kb + (size_t)bh * (T_ * HD_);
  const unsigned short* Vp = vb + (size_t)bh * (T_ * HD_);

  // Q fragments, two 16-row halves per wave (rows qt0 + 32*w2 + 16h + r16), pre-scaled 1/8
  bf16x8 qf[2][2];
  #pragma unroll
  for (int h = 0; h < 2; ++h) {
    int qrow = qt0 + w2 * 32 + h * 16 + r16;
    #pragma unroll
    for (int kk = 0; kk < 2; ++kk) {
      us8v raw = *(const us8v*)(Q + (size_t)qrow * HD_ + kk * 32 + g * 8);
      bf16x8 qv;
      #pragma unroll
      for (int j = 0; j < 8; ++j) qv[j] = (__bf16)(bf2f(raw[j]) * 0.125f);
      qf[h][kk] = qv;
    }
  }

  f32x4 o[2][4];
  #pragma unroll
  for (int h = 0; h < 2; ++h)
    #pragma unroll
    for (int c = 0; c < 4; ++c) o[h][c] = (f32x4){0.f, 0.f, 0.f, 0.f};
  float mrun[2] = {-__builtin_inff(), -__builtin_inff()};
  float lrun[2] = {0.f, 0.f};

  // staging constants: K slots t+128i (i=0..3); kp == (t&7)^(kr&7)
  const int kr0 = (t +   0) >> 3, kp0 = (t & 7) ^ (kr0 & 7);
  const int kr1 = (t + 128) >> 3, kp1 = (t & 7) ^ (kr1 & 7);
  const int kr2 = (t + 256) >> 3, kp2 = (t & 7) ^ (kr2 & 7);
  const int kr3 = (t + 384) >> 3, kp3 = (t & 7) ^ (kr3 & 7);
  // V: wave w2 owns d-rows [32*w2, 32*w2+32) as octets 0..3; lane owns kv row `lane`.
  const int colp = (lane & 32) | ((lane & 12) << 1) | ((lane >> 2) & 4) | (lane & 3);
  const int cslot = colp >> 3, cwithin = colp & 7;
  const int dbase = w2 * 32;

#define AK_STAGE(kv0, buf)                                                     \
  {                                                                            \
    unsigned short* Kd = LDS + (buf) * 4096;                                   \
    gload16(Kp + (size_t)((kv0) + kr0) * HD_ + kp0 * 8, Kd + (t +   0) * 8);   \
    gload16(Kp + (size_t)((kv0) + kr1) * HD_ + kp1 * 8, Kd + (t + 128) * 8);   \
    gload16(Kp + (size_t)((kv0) + kr2) * HD_ + kp2 * 8, Kd + (t + 256) * 8);   \
    gload16(Kp + (size_t)((kv0) + kr3) * HD_ + kp3 * 8, Kd + (t + 384) * 8);   \
  }
#define AV_LOAD(kv0, n0, n1, n2, n3)                                           \
  n0 = *(const us8v*)(Vp + (size_t)((kv0) + lane) * HD_ + dbase +  0);         \
  n1 = *(const us8v*)(Vp + (size_t)((kv0) + lane) * HD_ + dbase +  8);         \
  n2 = *(const us8v*)(Vp + (size_t)((kv0) + lane) * HD_ + dbase + 16);         \
  n3 = *(const us8v*)(Vp + (size_t)((kv0) + lane) * HD_ + dbase + 24);

  // prologue: batches 0 and 1 (8 VMEM ops per batch: 4 K-DMA + 4 nv)
  us8v nvA0, nvA1, nvA2, nvA3, nvB0, nvB1, nvB2, nvB3;
  AK_STAGE(kvLo * 64, 0);
  AV_LOAD(kvLo * 64, nvA0, nvA1, nvA2, nvA3);
  if (len > 1) {
    AK_STAGE((kvLo + 1) * 64, 1);
    AV_LOAD((kvLo + 1) * 64, nvB0, nvB1, nvB2, nvB3);
  }

  for (int ii = 0; ii < len; ++ii) {
    const int it = kvLo + ii;
    const unsigned short* Kl = LDS + (ii % 3) * 4096;
    unsigned short* Vt = LDS + 12288 + (ii & 1) * 4096;

    if (ii + 1 < len) { asm volatile("s_waitcnt vmcnt(8)" ::: "memory"); }
    else              { asm volatile("s_waitcnt vmcnt(0)" ::: "memory"); }
    {
      us8v v0, v1, v2, v3;
      if (ii & 1) { v0 = nvB0; v1 = nvB1; v2 = nvB2; v3 = nvB3; }
      else        { v0 = nvA0; v1 = nvA1; v2 = nvA2; v3 = nvA3; }
      #pragma unroll
      for (int u = 0; u < 8; ++u) {
        int d = dbase + u;                              // d&7 == u
        Vt[d * 64 + ((cslot ^ u) << 3) + cwithin] = v0[u];
      }
      #pragma unroll
      for (int u = 0; u < 8; ++u) {
        int d = dbase + 8 + u;
        Vt[d * 64 + ((cslot ^ u) << 3) + cwithin] = v1[u];
      }
      #pragma unroll
      for (int u = 0; u < 8; ++u) {
        int d = dbase + 16 + u;
        Vt[d * 64 + ((cslot ^ u) << 3) + cwithin] = v2[u];
      }
      #pragma unroll
      for (int u = 0; u < 8; ++u) {
        int d = dbase + 24 + u;
        Vt[d * 64 + ((cslot ^ u) << 3) + cwithin] = v3[u];
      }
    }
    __syncthreads();

    if (ii + 2 < len) {    // issue batch ii+2 (K buf (ii+2)%3, nv set ii&1 just freed)
      const int kn = (it + 2) * 64;
      AK_STAGE(kn, (ii + 2) % 3);
      if (ii & 1) { AV_LOAD(kn, nvB0, nvB1, nvB2, nvB3); }
      else        { AV_LOAD(kn, nvA0, nvA1, nvA2, nvA3); }
    }

    {
      // S^T: s4t[h][c][j] = S[q = qt0+32w2+16h+r16][kv = it*64 + 16c + 4g + j]
      f32x4 s4t[2][4];
      #pragma unroll
      for (int h = 0; h < 2; ++h)
        #pragma unroll
        for (int c = 0; c < 4; ++c) s4t[h][c] = (f32x4){0.f, 0.f, 0.f, 0.f};
      __builtin_amdgcn_s_setprio(1);
      #pragma unroll
      for (int c = 0; c < 4; ++c)
        #pragma unroll
        for (int kk = 0; kk < 2; ++kk) {
          int r = c * 16 + r16;
          int ps = (kk * 4 + g) ^ (r & 7);
          bf16x8 kf = *(const bf16x8*)(Kl + r * 64 + ps * 8);   // 1 read, 2 MFMAs
          s4t[0][c] = mfma16(kf, qf[0][kk], s4t[0][c]);
          s4t[1][c] = mfma16(kf, qf[1][kk], s4t[1][c]);
        }
      __builtin_amdgcn_s_setprio(0);
      if (it == tile) {   // diagonal: mask kv_local > tile-local q row
        #pragma unroll
        for (int h = 0; h < 2; ++h) {
          int qloc = w2 * 32 + h * 16 + r16;
          #pragma unroll
          for (int c = 0; c < 4; ++c)
            #pragma unroll
            for (int j = 0; j < 4; ++j)
              if (c * 16 + g * 4 + j > qloc) s4t[h][c][j] = -1e30f;
        }
      }
      // online softmax per half (max3 + defer-max + tree-sum, v13-verified)
      bf16x8 pf[2][2];
      #pragma unroll
      for (int h = 0; h < 2; ++h) {
        float t0 = fmaxf(fmaxf(s4t[h][0][0], s4t[h][0][1]), s4t[h][0][2]);
        float t1 = fmaxf(fmaxf(s4t[h][0][3], s4t[h][1][0]), s4t[h][1][1]);
        float t2 = fmaxf(fmaxf(s4t[h][1][2], s4t[h][1][3]), s4t[h][2][0]);
        float t3 = fmaxf(fmaxf(s4t[h][2][1], s4t[h][2][2]), s4t[h][2][3]);
        float t4 = fmaxf(fmaxf(s4t[h][3][0], s4t[h][3][1]), s4t[h][3][2]);
        float mx = fmaxf(fmaxf(fmaxf(t0, t1), fmaxf(t2, t3)),
                         fmaxf(t4, s4t[h][3][3]));
        mx = fmaxf(mx, __shfl_xor(mx, 16));
        mx = fmaxf(mx, __shfl_xor(mx, 32));
        if (!__all(mx - mrun[h] <= 8.0f)) {
          float mn = fmaxf(mrun[h], mx);
          float alpha = __expf(mrun[h] - mn);
          mrun[h] = mn;
          lrun[h] *= alpha;
          #pragma unroll
          for (int c = 0; c < 4; ++c)
            #pragma unroll
            for (int j = 0; j < 4; ++j) o[h][c][j] *= alpha;
        }
        float ps4[4];
        #pragma unroll
        for (int c = 0; c < 4; ++c) {
          #pragma unroll
          for (int j = 0; j < 4; ++j) s4t[h][c][j] = __expf(s4t[h][c][j] - mrun[h]);
          ps4[c] = (s4t[h][c][0] + s4t[h][c][1]) + (s4t[h][c][2] + s4t[h][c][3]);
        }
        float rs = (ps4[0] + ps4[1]) + (ps4[2] + ps4[3]);
        rs += __shfl_xor(rs, 16);
        rs += __shfl_xor(rs, 32);
        lrun[h] += rs;
        #pragma unroll
        for (int kk = 0; kk < 2; ++kk) {
          bf16x8 p;
          #pragma unroll
          for (int j = 0; j < 4; ++j) {
            p[j]     = (__bf16)s4t[h][2 * kk][j];
            p[4 + j] = (__bf16)s4t[h][2 * kk + 1][j];
          }
          pf[h][kk] = p;
        }
      }
      // O^T += V^T @ P^T : 1 vf read feeds 2 MFMAs
      __builtin_amdgcn_s_setprio(1);
      #pragma unroll
      for (int c = 0; c < 4; ++c) {
        int rv = c * 16 + r16;
        #pragma unroll
        for (int kk = 0; kk < 2; ++kk) {
          int slot = (4 * kk + g) ^ (r16 & 7);
          bf16x8 vf = *(const bf16x8*)(Vt + rv * 64 + slot * 8);
          o[0][c] = mfma16(vf, pf[0][kk], o[0][c]);
          o[1][c] = mfma16(vf, pf[1][kk], o[1][c]);
        }
      }
      __builtin_amdgcn_s_setprio(0);
    }
  }

  // epilogue: per-wave region in the unused K buffer (len%3), two 16-row passes
  unsigned short* ep = LDS + (len % 3) * 4096 + w2 * 1024;
  #pragma unroll
  for (int h = 0; h < 2; ++h) {
    if (mode && g == 0) {   // (m,l) for split merge
      int prow = (bh * 16 + (tile - 16)) * 64 + w2 * 32 + h * 16 + r16;
      float* mlp = mlbuf + (size_t)prow * 4;
      if (mode == 1) { mlp[0] = mrun[h]; mlp[1] = lrun[h]; }
      else           { mlp[2] = mrun[h]; mlp[3] = lrun[h]; }
    }
    float inv = 1.f / lrun[h];
    #pragma unroll
    for (int c = 0; c < 4; ++c) {
      us4v pk;
      #pragma unroll
      for (int j = 0; j < 4; ++j) pk[j] = f2bf(o[h][c][j] * inv);
      int slot = (4 * c + g) ^ r16;
      *(us4v*)(ep + r16 * 64 + slot * 4) = pk;
    }
    asm volatile("s_waitcnt lgkmcnt(0)" ::: "memory");
    __builtin_amdgcn_sched_barrier(0);
    {
      int q = lane >> 2, seg = lane & 3;
      us4v a0 = *(const us4v*)(ep + q * 64 + (((seg * 4 + 0) ^ q) & 15) * 4);
      us4v a1 = *(const us4v*)(ep + q * 64 + (((seg * 4 + 1) ^ q) & 15) * 4);
      us4v a2 = *(const us4v*)(ep + q * 64 + (((seg * 4 + 2) ^ q) & 15) * 4);
      us4v a3 = *(const us4v*)(ep + q * 64 + (((seg * 4 + 3) ^ q) & 15) * 4);
      us8v o0 = {a0[0],a0[1],a0[2],a0[3],a1[0],a1[1],a1[2],a1[3]};
      us8v o1 = {a2[0],a2[1],a2[2],a2[3],a3[0],a3[1],a3[2],a3[3]};
      if (mode != 2) {
        size_t rowg = (size_t)(bh >> 4) * T_ + qt0 + w2 * 32 + h * 16 + q;
        int colg = (bh & 15) * 64 + seg * 16;
        *(us8v*)(ao + rowg * C_ + colg)     = o0;
        *(us8v*)(ao + rowg * C_ + colg + 8) = o1;
      } else {
        size_t prow = (size_t)(bh * 16 + (tile - 16)) * 64 + w2 * 32 + h * 16 + q;
        *(us8v*)(partB + prow * 64 + seg * 16)     = o0;
        *(us8v*)(partB + prow * 64 + seg * 16 + 8) = o1;
      }
    }
    asm volatile("s_waitcnt lgkmcnt(0)" ::: "memory");
    __builtin_amdgcn_sched_barrier(0);
  }
#undef AK_STAGE
#undef AV_LOAD
}

// ---------------- merge kernel: combine halfA (in ao) with halfB ----------------
__global__ __launch_bounds__(256) void attn_merge_kernel(unsigned short* __restrict__ ao,
                                                         const unsigned short* __restrict__ partB,
                                                         const float* __restrict__ mlbuf) {
  const int blk = blockIdx.x;          // 512 = 32 bh x 16 ti
  const int bh = blk >> 4, ti = blk & 15;
  const int t = threadIdx.x;
  const int row = t >> 2, seg = t & 3;
  const size_t prow = (size_t)(bh * 16 + ti) * 64 + row;
  const float* mlp = mlbuf + prow * 4;
  float mA = mlp[0], lA = mlp[1], mB = mlp[2], lB = mlp[3];
  float m = fmaxf(mA, mB);
  float wA = lA * __expf(mA - m), wB = lB * __expf(mB - m);
  float rinv = 1.f / (wA + wB);
  wA *= rinv; wB *= rinv;
  size_t rowg = (size_t)(bh >> 4) * T_ + (16 + ti) * 64 + row;
  unsigned short* aop = ao + rowg * C_ + (bh & 15) * 64 + seg * 16;
  const unsigned short* obp = partB + prow * 64 + seg * 16;
  us8v oa0 = *(const us8v*)(aop);
  us8v oa1 = *(const us8v*)(aop + 8);
  us8v ob0 = *(const us8v*)(obp);
  us8v ob1 = *(const us8v*)(obp + 8);
  us8v r0, r1;
  #pragma unroll
  for (int j = 0; j < 8; ++j) {
    r0[j] = f2bf(bf2f(oa0[j]) * wA + bf2f(ob0[j]) * wB);
    r1[j] = f2bf(bf2f(oa1[j]) * wA + bf2f(ob1[j]) * wB);
  }
  *(us8v*)(aop)     = r0;
  *(us8v*)(aop + 8) = r1;
}

// ---------------- launch ----------------
extern "C" void kernel_launch(void* const* d_in, const int* in_sizes, int n_in,
                              void* d_out, int out_size, void* d_ws, size_t ws_size,
                              hipStream_t stream) {
  const float* x      = (const float*)d_in[0];
  const float* w_qkv  = (const float*)d_in[1];
  const float* w_proj = (const float*)d_in[2];
  float* out = (float*)d_out;
  char* ws = (char*)d_ws;

  unsigned short* xb     = (unsigned short*)(ws);              // 8 MB (reused as ao)
  unsigned short* wqkvT  = (unsigned short*)(ws + 8388608);    // 6 MB (reused: partB+ml)
  unsigned short* wprojT = (unsigned short*)(ws + 14680064);   // 2 MB
  unsigned short* qb     = (unsigned short*)(ws + 16777216);   // 8 MB
  unsigned short* kb     = (unsigned short*)(ws + 25165824);   // 8 MB
  unsigned short* vb     = (unsigned short*)(ws + 33554432);   // 8 MB
  unsigned short* ao     = xb;
  unsigned short* partB  = wqkvT;                              // 4 MB
  float*          mlbuf  = (float*)(ws + 8388608 + 4194304);   // 512 KB

  prep_kernel<<<8192, 256, 0, stream>>>(x, xb, w_qkv, wqkvT, w_proj, wprojT);
  gemm_qkv_kernel<<<dim3(3 * C_ / 128, (B_ * T_) / 128), 256, 0, stream>>>(
      xb, wqkvT, qb, kb, vb);
  attn_kernel<<<dim3(1536), 128, 0, stream>>>(qb, kb, vb, ao, partB, mlbuf);
  attn_merge_kernel<<<512, 256, 0, stream>>>(ao, partB, mlbuf);
  gemm_proj_kernel<<<dim3(C_ / 128, (B_ * T_) / 128), 256, 0, stream>>>(
      ao, wprojT, out);
}

// Round 19
// 120.555 us; speedup vs baseline: 2.1971x; 1.1388x over previous
//
#include <hip/hip_runtime.h>
#include <hip/hip_bf16.h>
#include <stdint.h>

typedef __bf16 bf16x8 __attribute__((ext_vector_type(8)));
typedef float f32x4 __attribute__((ext_vector_type(4)));
typedef unsigned short us4v __attribute__((ext_vector_type(4)));
typedef unsigned short us8v __attribute__((ext_vector_type(8)));

#define B_   2
#define T_   2048
#define C_   1024
#define NH_  16
#define HD_  64

__device__ __forceinline__ unsigned short f2bf(float f) {
  unsigned int u = __builtin_bit_cast(unsigned int, f);
  u += 0x7fffu + ((u >> 16) & 1u);           // RNE
  return (unsigned short)(u >> 16);
}
__device__ __forceinline__ float bf2f(unsigned short u) {
  unsigned int x = ((unsigned int)u) << 16;
  return __builtin_bit_cast(float, x);
}

__device__ __forceinline__ void gload16(const void* g, void* l) {
  __builtin_amdgcn_global_load_lds(
      (const __attribute__((address_space(1))) unsigned int*)g,
      (__attribute__((address_space(3))) unsigned int*)l, 16, 0, 0);
}

__device__ __forceinline__ f32x4 mfma16(bf16x8 a, bf16x8 b, f32x4 c) {
  return __builtin_amdgcn_mfma_f32_16x16x32_bf16(a, b, c, 0, 0, 0);
}

// ---------------- fused prep: cast_x + both weight transposes, ONE dispatch ----------------
__global__ __launch_bounds__(256) void prep_kernel(const float* __restrict__ x,
                                                   unsigned short* __restrict__ xb,
                                                   const float* __restrict__ w_qkv,
                                                   unsigned short* __restrict__ wqkvT,
                                                   const float* __restrict__ w_proj,
                                                   unsigned short* __restrict__ wprojT) {
  __shared__ float tile[32][33];
  const int b = blockIdx.x, t = threadIdx.x;
  if (b < 4096) {
    int i = b * 256 + t;
    float4 f = ((const float4*)x)[i];
    us4v o; o[0] = f2bf(f.x); o[1] = f2bf(f.y); o[2] = f2bf(f.z); o[3] = f2bf(f.w);
    ((us4v*)xb)[i] = o;
    return;
  }
  const float* w; unsigned short* wT; int N, tb;
  if (b < 7168) { tb = b - 4096; w = w_qkv;  wT = wqkvT;  N = 3 * C_; }
  else          { tb = b - 7168; w = w_proj; wT = wprojT; N = C_; }
  const int nx = N / 32;
  const int n0 = (tb % nx) * 32, k0 = (tb / nx) * 32;
  const int tx = t & 31, ty = t >> 5;   // 32 x 8
  #pragma unroll
  for (int i = 0; i < 4; ++i)
    tile[ty + 8*i][tx] = w[(size_t)(k0 + ty + 8*i) * N + n0 + tx];
  __syncthreads();
  #pragma unroll
  for (int i = 0; i < 4; ++i)
    wT[(size_t)(n0 + ty + 8*i) * C_ + k0 + tx] = f2bf(tile[tx][ty + 8*i]);
}

// ---------------- GEMM core (verified round 0 — structural ceiling ~870 TF) ----------------
__device__ __forceinline__ void gemm_core(const unsigned short* __restrict__ A,
                                          const unsigned short* __restrict__ Bt,
                                          int K, int m0, int n0,
                                          unsigned short* lA, unsigned short* lB,
                                          f32x4 acc[4][4]) {
  const int t = threadIdx.x;
  const int lane = t & 63, w = t >> 6;
  const int wm = w >> 1, wn = w & 1;
  const int g = lane >> 4, r16 = lane & 15;
  #pragma unroll
  for (int i = 0; i < 4; ++i)
    #pragma unroll
    for (int j = 0; j < 4; ++j) acc[i][j] = (f32x4){0.f, 0.f, 0.f, 0.f};

  for (int k0 = 0; k0 < K; k0 += 64) {
    #pragma unroll
    for (int i = 0; i < 4; ++i) {
      int slot = i * 256 + t;
      int r = slot >> 3, p = slot & 7;
      int q = p ^ (r & 7);
      gload16(A  + (size_t)(m0 + r) * K + k0 + q * 8, lA + slot * 8);
      gload16(Bt + (size_t)(n0 + r) * K + k0 + q * 8, lB + slot * 8);
    }
    asm volatile("s_waitcnt vmcnt(0)" ::: "memory");
    __syncthreads();

    bf16x8 af[4][2], bfr[4][2];
    #pragma unroll
    for (int mi = 0; mi < 4; ++mi)
      #pragma unroll
      for (int kk = 0; kk < 2; ++kk) {
        int r = wm * 64 + mi * 16 + r16;
        int ps = (kk * 4 + g) ^ (r & 7);
        af[mi][kk] = *(const bf16x8*)(lA + r * 64 + ps * 8);
      }
    #pragma unroll
    for (int ni = 0; ni < 4; ++ni)
      #pragma unroll
      for (int kk = 0; kk < 2; ++kk) {
        int r = wn * 64 + ni * 16 + r16;
        int ps = (kk * 4 + g) ^ (r & 7);
        bfr[ni][kk] = *(const bf16x8*)(lB + r * 64 + ps * 8);
      }
    #pragma unroll
    for (int mi = 0; mi < 4; ++mi)
      #pragma unroll
      for (int ni = 0; ni < 4; ++ni)
        #pragma unroll
        for (int kk = 0; kk < 2; ++kk)
          acc[mi][ni] = mfma16(af[mi][kk], bfr[ni][kk], acc[mi][ni]);
    __syncthreads();
  }
}

// XCD-aware bijective swizzle of the linear workgroup id (nwg % 8 == 0)
__device__ __forceinline__ int xcd_swz(int flat, int nwg) {
  int cpx = nwg >> 3;
  return (flat & 7) * cpx + (flat >> 3);
}

__global__ __launch_bounds__(256) void gemm_qkv_kernel(const unsigned short* __restrict__ xb,
                                                       const unsigned short* __restrict__ wT,
                                                       unsigned short* __restrict__ qb,
                                                       unsigned short* __restrict__ kb,
                                                       unsigned short* __restrict__ vb) {
  __shared__ unsigned short lA[128 * 64];
  __shared__ unsigned short lB[128 * 64];
  f32x4 acc[4][4];
  const int nbx = 3 * C_ / 128;
  int flat = xcd_swz(blockIdx.y * nbx + blockIdx.x, nbx * ((B_ * T_) / 128));
  const int m0 = (flat / nbx) * 128, n0 = (flat % nbx) * 128;
  gemm_core(xb, wT, C_, m0, n0, lA, lB, acc);
  const int t = threadIdx.x, lane = t & 63, w = t >> 6;
  const int wm = w >> 1, wn = w & 1, g = lane >> 4, r16 = lane & 15;
  #pragma unroll
  for (int mi = 0; mi < 4; ++mi)
    #pragma unroll
    for (int ni = 0; ni < 4; ++ni)
      #pragma unroll
      for (int j = 0; j < 4; ++j) {
        int gm = m0 + wm * 64 + mi * 16 + g * 4 + j;
        int gn = n0 + wn * 64 + ni * 16 + r16;
        int b = gm >> 11, tt = gm & 2047;
        int s = gn >> 10, rem = gn & 1023;
        int h = rem >> 6, d = rem & 63;
        unsigned short val = f2bf(acc[mi][ni][j]);
        size_t idx = ((size_t)(b * NH_ + h) * T_ + tt) * HD_ + d;
        if (s == 0)      qb[idx] = val;
        else if (s == 1) kb[idx] = val;
        else             vb[idx] = val;
      }
}

__global__ __launch_bounds__(256) void gemm_proj_kernel(const unsigned short* __restrict__ ab,
                                                        const unsigned short* __restrict__ wT,
                                                        float* __restrict__ out) {
  __shared__ unsigned short lA[128 * 64];
  __shared__ unsigned short lB[128 * 64];
  f32x4 acc[4][4];
  const int nbx = C_ / 128;
  int flat = xcd_swz(blockIdx.y * nbx + blockIdx.x, nbx * ((B_ * T_) / 128));
  const int m0 = (flat / nbx) * 128, n0 = (flat % nbx) * 128;
  gemm_core(ab, wT, C_, m0, n0, lA, lB, acc);
  const int t = threadIdx.x, lane = t & 63, w = t >> 6;
  const int wm = w >> 1, wn = w & 1, g = lane >> 4, r16 = lane & 15;
  #pragma unroll
  for (int mi = 0; mi < 4; ++mi)
    #pragma unroll
    for (int ni = 0; ni < 4; ++ni)
      #pragma unroll
      for (int j = 0; j < 4; ++j) {
        int gm = m0 + wm * 64 + mi * 16 + g * 4 + j;
        int gn = n0 + wn * 64 + ni * 16 + r16;
        out[(size_t)gm * C_ + gn] = acc[mi][ni][j];
      }
}

// ---------------- Flash attention v13 (verified rounds 13/15/16) ----------------
__global__ __launch_bounds__(256, 4) void attn_kernel(const unsigned short* __restrict__ qb,
                                                      const unsigned short* __restrict__ kb,
                                                      const unsigned short* __restrict__ vb,
                                                      unsigned short* __restrict__ ao,
                                                      unsigned short* __restrict__ partB,
                                                      float* __restrict__ mlbuf) {
  __shared__ unsigned short LDS[20480];
  const int L = blockIdx.x;
  const int inner = L >> 3;
  const int bh = (L & 7) * 4 + (inner / 48);
  const int bx = inner % 48;
  int tile, kvLo, kvHi, mode;   // mode: 0=full, 1=halfA, 2=halfB
  if (bx < 16)      { tile = 16 + bx; kvLo = 0;  kvHi = 16;       mode = 1; }
  else if (bx < 32) { tile = 47 - bx; kvLo = 16; kvHi = tile + 1; mode = 2; }
  else              { tile = 47 - bx; kvLo = 0;  kvHi = tile + 1; mode = 0; }
  const int qt0 = tile * 64;
  const int len = kvHi - kvLo;
  const int t = threadIdx.x, lane = t & 63, w4 = t >> 6;   // w4 in 0..3
  const int g = lane >> 4, r16 = lane & 15;

  const unsigned short* Q  = qb + (size_t)bh * (T_ * HD_);
  const unsigned short* Kp = kb + (size_t)bh * (T_ * HD_);
  const unsigned short* Vp = vb + (size_t)bh * (T_ * HD_);

  // Q fragments (B-operand: lane holds Q[q=r16][k-octet g]), pre-scaled 1/8
  bf16x8 qf[2];
  {
    int qrow = qt0 + w4 * 16 + r16;
    #pragma unroll
    for (int kk = 0; kk < 2; ++kk) {
      us8v raw = *(const us8v*)(Q + (size_t)qrow * HD_ + kk * 32 + g * 8);
      bf16x8 qv;
      #pragma unroll
      for (int j = 0; j < 8; ++j) qv[j] = (__bf16)(bf2f(raw[j]) * 0.125f);
      qf[kk] = qv;
    }
  }

  f32x4 o[4];
  #pragma unroll
  for (int c = 0; c < 4; ++c) o[c] = (f32x4){0.f, 0.f, 0.f, 0.f};
  float mrun = -__builtin_inff(), lrun = 0.f;

  // staging constants (verified formulas)
  const int kr0 = t >> 3,         kp0 = (t & 7) ^ (kr0 & 7);   // rows 0..31
  const int kr1 = (t + 256) >> 3, kp1 = (t & 7) ^ (kr1 & 7);   // rows 32..63
  const int colp = (lane & 32) | ((lane & 12) << 1) | ((lane >> 2) & 4) | (lane & 3);
  const int cslot = colp >> 3, cwithin = colp & 7;

  // prologue: batches 0 and 1 (K DMA then V regs; 4 VMEM ops per batch)
  gload16(Kp + (size_t)(kvLo * 64 + kr0) * HD_ + kp0 * 8, LDS + t * 8);
  gload16(Kp + (size_t)(kvLo * 64 + kr1) * HD_ + kp1 * 8, LDS + (t + 256) * 8);
  us8v nvA0 = *(const us8v*)(Vp + (size_t)(kvLo * 64 + lane) * HD_ + w4 * 16);
  us8v nvA1 = *(const us8v*)(Vp + (size_t)(kvLo * 64 + lane) * HD_ + w4 * 16 + 8);
  us8v nvB0, nvB1;
  if (len > 1) {
    const int k1 = (kvLo + 1) * 64;
    gload16(Kp + (size_t)(k1 + kr0) * HD_ + kp0 * 8, LDS + 4096 + t * 8);
    gload16(Kp + (size_t)(k1 + kr1) * HD_ + kp1 * 8, LDS + 4096 + (t + 256) * 8);
    nvB0 = *(const us8v*)(Vp + (size_t)(k1 + lane) * HD_ + w4 * 16);
    nvB1 = *(const us8v*)(Vp + (size_t)(k1 + lane) * HD_ + w4 * 16 + 8);
  }

  for (int ii = 0; ii < len; ++ii) {
    const int it = kvLo + ii;
    const unsigned short* Kl = LDS + (ii % 3) * 4096;
    unsigned short* Vt = LDS + 12288 + (ii & 1) * 4096;

    if (ii + 1 < len) { asm volatile("s_waitcnt vmcnt(4)" ::: "memory"); }
    else              { asm volatile("s_waitcnt vmcnt(0)" ::: "memory"); }
    {
      us8v v0, v1;
      if (ii & 1) { v0 = nvB0; v1 = nvB1; } else { v0 = nvA0; v1 = nvA1; }
      #pragma unroll
      for (int u = 0; u < 8; ++u) {
        int d = w4 * 16 + u;                             // d&7 == u
        Vt[d * 64 + ((cslot ^ u) << 3) + cwithin] = v0[u];
      }
      #pragma unroll
      for (int u = 0; u < 8; ++u) {
        int d = w4 * 16 + 8 + u;
        Vt[d * 64 + ((cslot ^ u) << 3) + cwithin] = v1[u];
      }
    }
    __syncthreads();

    if (ii + 2 < len) {    // issue batch ii+2 (buf (ii+2)%3, nv set ii&1 — just freed)
      const int kn = (it + 2) * 64;
      unsigned short* Kn = LDS + ((ii + 2) % 3) * 4096;
      gload16(Kp + (size_t)(kn + kr0) * HD_ + kp0 * 8, Kn + t * 8);
      gload16(Kp + (size_t)(kn + kr1) * HD_ + kp1 * 8, Kn + (t + 256) * 8);
      if (ii & 1) {
        nvB0 = *(const us8v*)(Vp + (size_t)(kn + lane) * HD_ + w4 * 16);
        nvB1 = *(const us8v*)(Vp + (size_t)(kn + lane) * HD_ + w4 * 16 + 8);
      } else {
        nvA0 = *(const us8v*)(Vp + (size_t)(kn + lane) * HD_ + w4 * 16);
        nvA1 = *(const us8v*)(Vp + (size_t)(kn + lane) * HD_ + w4 * 16 + 8);
      }
    }

    {
      // S^T = K @ Q^T : s4t[c][j] = S[q=r16-row][kv = it*64 + 16c + 4g + j]
      f32x4 s4t[4];
      #pragma unroll
      for (int c = 0; c < 4; ++c) s4t[c] = (f32x4){0.f, 0.f, 0.f, 0.f};
      __builtin_amdgcn_s_setprio(1);
      #pragma unroll
      for (int c = 0; c < 4; ++c)
        #pragma unroll
        for (int kk = 0; kk < 2; ++kk) {
          int r = c * 16 + r16;
          int ps = (kk * 4 + g) ^ (r & 7);
          bf16x8 kf = *(const bf16x8*)(Kl + r * 64 + ps * 8);
          s4t[c] = mfma16(kf, qf[kk], s4t[c]);
        }
      __builtin_amdgcn_s_setprio(0);
      if (it == tile) {   // diagonal tile: mask kv_local > q_local
        int qloc = w4 * 16 + r16;
        #pragma unroll
        for (int c = 0; c < 4; ++c)
          #pragma unroll
          for (int j = 0; j < 4; ++j)
            if (c * 16 + g * 4 + j > qloc) s4t[c][j] = -1e30f;
      }
      // row max via max3-triples
      float t0 = fmaxf(fmaxf(s4t[0][0], s4t[0][1]), s4t[0][2]);
      float t1 = fmaxf(fmaxf(s4t[0][3], s4t[1][0]), s4t[1][1]);
      float t2 = fmaxf(fmaxf(s4t[1][2], s4t[1][3]), s4t[2][0]);
      float t3 = fmaxf(fmaxf(s4t[2][1], s4t[2][2]), s4t[2][3]);
      float t4 = fmaxf(fmaxf(s4t[3][0], s4t[3][1]), s4t[3][2]);
      float mx = fmaxf(fmaxf(fmaxf(t0, t1), fmaxf(t2, t3)),
                       fmaxf(t4, s4t[3][3]));
      mx = fmaxf(mx, __shfl_xor(mx, 16));
      mx = fmaxf(mx, __shfl_xor(mx, 32));
      // T13 defer-max: only rescale when max grew by > 8
      if (!__all(mx - mrun <= 8.0f)) {
        float mn = fmaxf(mrun, mx);
        float alpha = __expf(mrun - mn);
        mrun = mn;
        lrun *= alpha;
        #pragma unroll
        for (int c = 0; c < 4; ++c)
          #pragma unroll
          for (int j = 0; j < 4; ++j) o[c][j] *= alpha;
      }
      // P = exp(S - mrun); tree-sum
      float ps4[4];
      #pragma unroll
      for (int c = 0; c < 4; ++c) {
        #pragma unroll
        for (int j = 0; j < 4; ++j) s4t[c][j] = __expf(s4t[c][j] - mrun);
        ps4[c] = (s4t[c][0] + s4t[c][1]) + (s4t[c][2] + s4t[c][3]);
      }
      float rs = (ps4[0] + ps4[1]) + (ps4[2] + ps4[3]);
      rs += __shfl_xor(rs, 16);
      rs += __shfl_xor(rs, 32);
      lrun += rs;

      // P^T fragments in-register (B-operand): p[4h+e] = s4t[2kk+h][e]
      bf16x8 pf[2];
      #pragma unroll
      for (int kk = 0; kk < 2; ++kk) {
        bf16x8 p;
        #pragma unroll
        for (int j = 0; j < 4; ++j) {
          p[j]     = (__bf16)s4t[2 * kk][j];
          p[4 + j] = (__bf16)s4t[2 * kk + 1][j];
        }
        pf[kk] = p;
      }
      // O^T += V^T @ P^T : A-fragment = swizzled b128 from Vt
      __builtin_amdgcn_s_setprio(1);
      #pragma unroll
      for (int c = 0; c < 4; ++c) {
        int rv = c * 16 + r16;
        #pragma unroll
        for (int kk = 0; kk < 2; ++kk) {
          int slot = (4 * kk + g) ^ (r16 & 7);
          bf16x8 vf = *(const bf16x8*)(Vt + rv * 64 + slot * 8);
          o[c] = mfma16(vf, pf[kk], o[c]);
        }
      }
      __builtin_amdgcn_s_setprio(0);
    }
  }

  // write (m,l) for split halves (rows lane-owned by g==0 lanes)
  if (mode && g == 0) {
    int prow = (bh * 16 + (tile - 16)) * 64 + w4 * 16 + r16;
    float* mlp = mlbuf + (size_t)prow * 4;
    if (mode == 1) { mlp[0] = mrun; mlp[1] = lrun; }
    else           { mlp[2] = mrun; mlp[3] = lrun; }
  }

  // epilogue: normalized O -> unused K buffer (len%3) transpose -> coalesced store
  unsigned short* ep = LDS + (len % 3) * 4096 + w4 * 1024;
  float inv = 1.f / lrun;
  #pragma unroll
  for (int c = 0; c < 4; ++c) {
    us4v pk;
    #pragma unroll
    for (int j = 0; j < 4; ++j) pk[j] = f2bf(o[c][j] * inv);
    int slot = (4 * c + g) ^ r16;
    *(us4v*)(ep + r16 * 64 + slot * 4) = pk;
  }
  asm volatile("s_waitcnt lgkmcnt(0)" ::: "memory");
  __builtin_amdgcn_sched_barrier(0);
  {
    int q = lane >> 2, seg = lane & 3;
    us4v a0 = *(const us4v*)(ep + q * 64 + (((seg * 4 + 0) ^ q) & 15) * 4);
    us4v a1 = *(const us4v*)(ep + q * 64 + (((seg * 4 + 1) ^ q) & 15) * 4);
    us4v a2 = *(const us4v*)(ep + q * 64 + (((seg * 4 + 2) ^ q) & 15) * 4);
    us4v a3 = *(const us4v*)(ep + q * 64 + (((seg * 4 + 3) ^ q) & 15) * 4);
    us8v o0 = {a0[0],a0[1],a0[2],a0[3],a1[0],a1[1],a1[2],a1[3]};
    us8v o1 = {a2[0],a2[1],a2[2],a2[3],a3[0],a3[1],a3[2],a3[3]};
    if (mode != 2) {
      size_t rowg = (size_t)(bh >> 4) * T_ + qt0 + w4 * 16 + q;
      int colg = (bh & 15) * 64 + seg * 16;
      *(us8v*)(ao + rowg * C_ + colg)     = o0;
      *(us8v*)(ao + rowg * C_ + colg + 8) = o1;
    } else {
      size_t prow = (size_t)(bh * 16 + (tile - 16)) * 64 + w4 * 16 + q;
      *(us8v*)(partB + prow * 64 + seg * 16)     = o0;
      *(us8v*)(partB + prow * 64 + seg * 16 + 8) = o1;
    }
  }
}

// ---------------- merge kernel: combine halfA (in ao) with halfB ----------------
__global__ __launch_bounds__(256) void attn_merge_kernel(unsigned short* __restrict__ ao,
                                                         const unsigned short* __restrict__ partB,
                                                         const float* __restrict__ mlbuf) {
  const int blk = blockIdx.x;          // 512 = 32 bh x 16 ti
  const int bh = blk >> 4, ti = blk & 15;
  const int t = threadIdx.x;
  const int row = t >> 2, seg = t & 3;
  const size_t prow = (size_t)(bh * 16 + ti) * 64 + row;
  const float* mlp = mlbuf + prow * 4;
  float mA = mlp[0], lA = mlp[1], mB = mlp[2], lB = mlp[3];
  float m = fmaxf(mA, mB);
  float wA = lA * __expf(mA - m), wB = lB * __expf(mB - m);
  float rinv = 1.f / (wA + wB);
  wA *= rinv; wB *= rinv;
  size_t rowg = (size_t)(bh >> 4) * T_ + (16 + ti) * 64 + row;
  unsigned short* aop = ao + rowg * C_ + (bh & 15) * 64 + seg * 16;
  const unsigned short* obp = partB + prow * 64 + seg * 16;
  us8v oa0 = *(const us8v*)(aop);
  us8v oa1 = *(const us8v*)(aop + 8);
  us8v ob0 = *(const us8v*)(obp);
  us8v ob1 = *(const us8v*)(obp + 8);
  us8v r0, r1;
  #pragma unroll
  for (int j = 0; j < 8; ++j) {
    r0[j] = f2bf(bf2f(oa0[j]) * wA + bf2f(ob0[j]) * wB);
    r1[j] = f2bf(bf2f(oa1[j]) * wA + bf2f(ob1[j]) * wB);
  }
  *(us8v*)(aop)     = r0;
  *(us8v*)(aop + 8) = r1;
}

// ---------------- launch ----------------
extern "C" void kernel_launch(void* const* d_in, const int* in_sizes, int n_in,
                              void* d_out, int out_size, void* d_ws, size_t ws_size,
                              hipStream_t stream) {
  const float* x      = (const float*)d_in[0];
  const float* w_qkv  = (const float*)d_in[1];
  const float* w_proj = (const float*)d_in[2];
  float* out = (float*)d_out;
  char* ws = (char*)d_ws;

  unsigned short* xb     = (unsigned short*)(ws);              // 8 MB (reused as ao)
  unsigned short* wqkvT  = (unsigned short*)(ws + 8388608);    // 6 MB (reused: partB+ml)
  unsigned short* wprojT = (unsigned short*)(ws + 14680064);   // 2 MB
  unsigned short* qb     = (unsigned short*)(ws + 16777216);   // 8 MB
  unsigned short* kb     = (unsigned short*)(ws + 25165824);   // 8 MB
  unsigned short* vb     = (unsigned short*)(ws + 33554432);   // 8 MB
  unsigned short* ao     = xb;
  unsigned short* partB  = wqkvT;                              // 4 MB
  float*          mlbuf  = (float*)(ws + 8388608 + 4194304);   // 512 KB

  prep_kernel<<<8192, 256, 0, stream>>>(x, xb, w_qkv, wqkvT, w_proj, wprojT);
  gemm_qkv_kernel<<<dim3(3 * C_ / 128, (B_ * T_) / 128), 256, 0, stream>>>(
      xb, wqkvT, qb, kb, vb);
  attn_kernel<<<dim3(1536), 256, 0, stream>>>(qb, kb, vb, ao, partB, mlbuf);
  attn_merge_kernel<<<512, 256, 0, stream>>>(ao, partB, mlbuf);
  gemm_proj_kernel<<<dim3(C_ / 128, (B_ * T_) / 128), 256, 0, stream>>>(
      ao, wprojT, out);
}